// Round 1
// baseline (112.630 us; speedup 1.0000x reference)
//
#include <hip/hip_runtime.h>

// loss = 2 * 0.5 * dot(colsum(a), colsum(b)), a,b: (16384, 512) fp32.
// Memory-bound: 67 MB read -> ~11 us floor at 6.3 TB/s.

#define COLS    512
#define MAXREPL 16
#define NBLK    1024
#define NTHR    256

// ws layout: [repl][COLS] for a, then [repl][COLS] for b.

__global__ void zero_ws_kernel(float* __restrict__ ws, int count) {
    int i = blockIdx.x * blockDim.x + threadIdx.x;
    if (i < count) ws[i] = 0.0f;
}

__global__ __launch_bounds__(NTHR) void colsum_kernel(
        const float4* __restrict__ a, const float4* __restrict__ b,
        float* __restrict__ wsa, float* __restrict__ wsb,
        int n4, int repl) {
    const int tid  = threadIdx.x;
    const int gtid = blockIdx.x * NTHR + tid;
    const int NT   = NBLK * NTHR;          // multiple of 128 -> fixed column group

    float4 sa = make_float4(0.f, 0.f, 0.f, 0.f);
    float4 sb = make_float4(0.f, 0.f, 0.f, 0.f);

    for (int v = gtid; v < n4; v += NT) {
        float4 x = a[v];
        sa.x += x.x; sa.y += x.y; sa.z += x.z; sa.w += x.w;
    }
    for (int v = gtid; v < n4; v += NT) {
        float4 y = b[v];
        sb.x += y.x; sb.y += y.y; sb.z += y.z; sb.w += y.w;
    }

    // threads t and t+128 hold the same 4-column group -> LDS reduce 256->128
    __shared__ float4 lds_a[128];
    __shared__ float4 lds_b[128];
    if (tid >= 128) {
        lds_a[tid - 128] = sa;
        lds_b[tid - 128] = sb;
    }
    __syncthreads();
    if (tid < 128) {
        float4 oa = lds_a[tid];
        float4 ob = lds_b[tid];
        sa.x += oa.x; sa.y += oa.y; sa.z += oa.z; sa.w += oa.w;
        sb.x += ob.x; sb.y += ob.y; sb.z += ob.z; sb.w += ob.w;

        const int c = 4 * (tid & 127);           // column base (blockIdx*256 % 128 == 0)
        const int r = blockIdx.x % repl;         // replica to spread atomic contention
        float* pa = wsa + r * COLS + c;
        float* pb = wsb + r * COLS + c;
        atomicAdd(pa + 0, sa.x); atomicAdd(pa + 1, sa.y);
        atomicAdd(pa + 2, sa.z); atomicAdd(pa + 3, sa.w);
        atomicAdd(pb + 0, sb.x); atomicAdd(pb + 1, sb.y);
        atomicAdd(pb + 2, sb.z); atomicAdd(pb + 3, sb.w);
    }
}

__global__ __launch_bounds__(256) void dot_kernel(
        const float* __restrict__ wsa, const float* __restrict__ wsb,
        float* __restrict__ out, int repl) {
    float s = 0.f;
    for (int c = threadIdx.x; c < COLS; c += 256) {
        float sa = 0.f, sb = 0.f;
        for (int r = 0; r < repl; ++r) {
            sa += wsa[r * COLS + c];
            sb += wsb[r * COLS + c];
        }
        s += sa * sb;
    }
    // wave(64) butterfly reduce
    for (int off = 32; off > 0; off >>= 1) s += __shfl_down(s, off, 64);
    __shared__ float w[4];
    if ((threadIdx.x & 63) == 0) w[threadIdx.x >> 6] = s;
    __syncthreads();
    if (threadIdx.x == 0) {
        // 2 * lambd = 2 * 0.5 = 1.0
        out[0] = 1.0f * (w[0] + w[1] + w[2] + w[3]);
    }
}

extern "C" void kernel_launch(void* const* d_in, const int* in_sizes, int n_in,
                              void* d_out, int out_size, void* d_ws, size_t ws_size,
                              hipStream_t stream) {
    const float4* a = (const float4*)d_in[0];
    const float4* b = (const float4*)d_in[1];
    float* out = (float*)d_out;

    const int n_elems = in_sizes[0];        // 16384*512
    const int n4 = n_elems / 4;             // float4 count per matrix

    // replica count bounded by workspace size (needs 2*repl*COLS floats)
    int repl = (int)(ws_size / (2u * COLS * sizeof(float)));
    if (repl > MAXREPL) repl = MAXREPL;
    if (repl < 1) repl = 1;

    float* wsa = (float*)d_ws;
    float* wsb = wsa + repl * COLS;

    const int zero_count = 2 * repl * COLS;
    const int zero_blocks = (zero_count + 255) / 256;
    zero_ws_kernel<<<zero_blocks, 256, 0, stream>>>(wsa, zero_count);

    colsum_kernel<<<NBLK, NTHR, 0, stream>>>(a, b, wsa, wsb, n4, repl);

    dot_kernel<<<1, 256, 0, stream>>>(wsa, wsb, out, repl);
}

// Round 2
// 108.822 us; speedup vs baseline: 1.0350x; 1.0350x over previous
//
#include <hip/hip_runtime.h>

// loss = 2*0.5 * dot(colsum(a), colsum(b)), a,b: (16384, 512) fp32.
// Memory-bound: 67 MB read -> ~11 us floor at 6.3 TB/s achievable.
//
// R2: no atomics in the hot path. Stage-1 stores per-block column partials
// (pure coalesced stores, no init needed); stage-2 reduces the 4 MB of
// partials with coalesced 16-col-wide wave tasks and 32 total atomicAdds
// into out[0] (zeroed by a memset node).

#define ROWS  16384
#define COLS  512
#define NBLK1 1024
#define NTHR1 256
#define N4    ((ROWS * COLS) / 4)   // 2,097,152 float4 per matrix
#define NT1   (NBLK1 * NTHR1)       // 262,144 -> exactly 8 iters/thread

// ws layout: pa[1024][512] floats, then pb[1024][512] floats (4 MB total).

__global__ __launch_bounds__(NTHR1) void colsum_partial(
        const float4* __restrict__ a, const float4* __restrict__ b,
        float4* __restrict__ pa, float4* __restrict__ pb) {
    const int tid = threadIdx.x;
    const int g0  = blockIdx.x * NTHR1 + tid;

    float4 sa = make_float4(0.f, 0.f, 0.f, 0.f);
    float4 sb = make_float4(0.f, 0.f, 0.f, 0.f);

    // stride NT1 is a multiple of 128 -> each thread's 4-column group is fixed
#pragma unroll
    for (int i = 0; i < 8; ++i) {
        float4 x = a[g0 + i * NT1];
        sa.x += x.x; sa.y += x.y; sa.z += x.z; sa.w += x.w;
    }
#pragma unroll
    for (int i = 0; i < 8; ++i) {
        float4 y = b[g0 + i * NT1];
        sb.x += y.x; sb.y += y.y; sb.z += y.z; sb.w += y.w;
    }

    // threads t and t+128 hold the same 4-column group -> fold 256->128
    __shared__ float4 la[128];
    __shared__ float4 lb[128];
    if (tid >= 128) {
        la[tid - 128] = sa;
        lb[tid - 128] = sb;
    }
    __syncthreads();
    if (tid < 128) {
        float4 oa = la[tid];
        float4 ob = lb[tid];
        sa.x += oa.x; sa.y += oa.y; sa.z += oa.z; sa.w += oa.w;
        sb.x += ob.x; sb.y += ob.y; sb.z += ob.z; sb.w += ob.w;
        // thread t holds cols 4t..4t+3; coalesced float4 store, row = blockIdx
        pa[blockIdx.x * 128 + tid] = sa;
        pb[blockIdx.x * 128 + tid] = sb;
    }
}

// One wave (64 thr) per 16-column group; 32 blocks cover 512 cols.
// Lane l handles col = g*16 + (l&15), row-class r0 = l>>4 (4 rows/iter,
// 4 consecutive 64 B lines per load instruction -> fully coalesced).
__global__ __launch_bounds__(64) void reduce_dot(
        const float* __restrict__ pa, const float* __restrict__ pb,
        float* __restrict__ out) {
    const int l   = threadIdx.x;
    const int col = blockIdx.x * 16 + (l & 15);
    const int r0  = l >> 4;

    float va = 0.f, vb = 0.f;
#pragma unroll 8
    for (int r = r0; r < NBLK1; r += 4) {
        va += pa[r * COLS + col];
        vb += pb[r * COLS + col];
    }
    // fold the 4 row-classes (lanes with equal l&15)
    va += __shfl_xor(va, 16, 64); va += __shfl_xor(va, 32, 64);
    vb += __shfl_xor(vb, 16, 64); vb += __shfl_xor(vb, 32, 64);
    float p = va * vb;  // per-column product (replicated 4x across groups)
    // sum across the 16 columns
    p += __shfl_xor(p, 1, 64);
    p += __shfl_xor(p, 2, 64);
    p += __shfl_xor(p, 4, 64);
    p += __shfl_xor(p, 8, 64);
    if (l == 0) {
        // 2 * lambd = 1.0
        atomicAdd(out, p);
    }
}

extern "C" void kernel_launch(void* const* d_in, const int* in_sizes, int n_in,
                              void* d_out, int out_size, void* d_ws, size_t ws_size,
                              hipStream_t stream) {
    const float4* a = (const float4*)d_in[0];
    const float4* b = (const float4*)d_in[1];
    float* out = (float*)d_out;

    float4* pa = (float4*)d_ws;                     // [1024][128] float4
    float4* pb = pa + NBLK1 * (COLS / 4);           // [1024][128] float4

    hipMemsetAsync(out, 0, sizeof(float), stream);

    colsum_partial<<<NBLK1, NTHR1, 0, stream>>>(a, b, pa, pb);

    reduce_dot<<<COLS / 16, 64, 0, stream>>>((const float*)pa, (const float*)pb, out);
}

// Round 4
// 100.536 us; speedup vs baseline: 1.1203x; 1.0824x over previous
//
#include <hip/hip_runtime.h>

// loss = 2*0.5 * dot(colsum(a), colsum(b)), a,b: (16384, 512) fp32.
// Memory-bound: 67 MB read -> ~11 us floor at 6.3 TB/s achievable.
// Measured: dur_us includes ~85-90 us of harness reset (256 MiB ws poison +
// 134 MB input restore); controllable portion is ~18 us. R3/R4 trims it:
//  - no memset node (stage1 zeroes out[0]; kernel boundary orders it)
//  - 512 stage-1 blocks -> 2 MB partials (was 4 MB)
//  - stage-2 4x thread parallelism, shfl folds
//  - interleaved nontemporal input loads (native ext_vector_type for builtin)

#define ROWS  16384
#define COLS  512
#define PB    512                   // stage-1 blocks == partial rows
#define NTHR  256
#define N4    ((ROWS * COLS) / 4)   // 2,097,152 float4 per matrix
#define NT    (PB * NTHR)           // 131,072 -> exactly 16 iters/thread

typedef float vfloat4 __attribute__((ext_vector_type(4)));

__device__ __forceinline__ vfloat4 ntload(const vfloat4* p) {
    return __builtin_nontemporal_load(p);
}

// ws: pa[512][512] floats (1 MB), pb[512][512] floats (1 MB)

__global__ __launch_bounds__(NTHR) void colsum_partial(
        const vfloat4* __restrict__ a, const vfloat4* __restrict__ b,
        vfloat4* __restrict__ pa, vfloat4* __restrict__ pb,
        float* __restrict__ out) {
    const int tid = threadIdx.x;
    const int g0  = blockIdx.x * NTHR + tid;

    if (blockIdx.x == 0 && tid == 0) out[0] = 0.0f;  // for stage-2 atomics

    vfloat4 sa = (vfloat4)(0.f);
    vfloat4 sb = (vfloat4)(0.f);

    // stride NT is a multiple of 128 -> each thread's 4-column group is fixed
#pragma unroll
    for (int i = 0; i < 16; ++i) {
        vfloat4 x = ntload(a + g0 + i * NT);
        vfloat4 y = ntload(b + g0 + i * NT);
        sa += x;
        sb += y;
    }

    // threads t and t+128 hold the same 4-column group -> fold 256->128
    __shared__ vfloat4 la[128];
    __shared__ vfloat4 lb[128];
    if (tid >= 128) {
        la[tid - 128] = sa;
        lb[tid - 128] = sb;
    }
    __syncthreads();
    if (tid < 128) {
        sa += la[tid];
        sb += lb[tid];
        pa[blockIdx.x * 128 + tid] = sa;   // coalesced 16B store
        pb[blockIdx.x * 128 + tid] = sb;
    }
}

// 32 blocks x 256 threads; block b owns cols 16b..16b+15.
// thread t: col = 16b + (t&15), row-class rc = t>>4 (16 classes over PB rows).
// Per wave load: 4 rows x 64 B contiguous -> 4 fully-used lines.
__global__ __launch_bounds__(NTHR) void reduce_dot(
        const float* __restrict__ pa, const float* __restrict__ pb,
        float* __restrict__ out) {
    const int t   = threadIdx.x;
    const int col = blockIdx.x * 16 + (t & 15);
    const int rc  = t >> 4;

    float va = 0.f, vb = 0.f;
#pragma unroll 8
    for (int r = rc; r < PB; r += 16) {
        va += pa[r * COLS + col];
        vb += pb[r * COLS + col];
    }
    // wave w covers row-classes 4w..4w+3; fold them (lanes l, l^16, l^32)
    va += __shfl_xor(va, 16, 64); va += __shfl_xor(va, 32, 64);
    vb += __shfl_xor(vb, 16, 64); vb += __shfl_xor(vb, 32, 64);

    __shared__ float sa4[4][16];
    __shared__ float sb4[4][16];
    const int wave = t >> 6, lane = t & 63;
    if (lane < 16) { sa4[wave][lane] = va; sb4[wave][lane] = vb; }
    __syncthreads();
    if (t < 16) {
        float ca = sa4[0][t] + sa4[1][t] + sa4[2][t] + sa4[3][t];
        float cb = sb4[0][t] + sb4[1][t] + sb4[2][t] + sb4[3][t];
        float p  = ca * cb;                     // per-column product
        p += __shfl_xor(p, 1, 64);
        p += __shfl_xor(p, 2, 64);
        p += __shfl_xor(p, 4, 64);
        p += __shfl_xor(p, 8, 64);
        if (t == 0) atomicAdd(out, p);          // 2*lambd = 1.0
    }
}

extern "C" void kernel_launch(void* const* d_in, const int* in_sizes, int n_in,
                              void* d_out, int out_size, void* d_ws, size_t ws_size,
                              hipStream_t stream) {
    const vfloat4* a = (const vfloat4*)d_in[0];
    const vfloat4* b = (const vfloat4*)d_in[1];
    float* out = (float*)d_out;

    vfloat4* pa = (vfloat4*)d_ws;               // [512][128] vfloat4
    vfloat4* pb = pa + PB * (COLS / 4);         // [512][128] vfloat4

    colsum_partial<<<PB, NTHR, 0, stream>>>(a, b, pa, pb, out);
    reduce_dot<<<COLS / 16, NTHR, 0, stream>>>((const float*)pa, (const float*)pb, out);
}